// Round 1
// baseline (632.244 us; speedup 1.0000x reference)
//
#include <hip/hip_runtime.h>
#include <hip/hip_bf16.h>

#define NPTS    524288
#define NG      64
#define GSZ     64
#define VOX     (GSZ*GSZ*GSZ)   // 262144
#define NODES   64

// Repack [G,C,D,H,W] fp32 -> [G,D,H,W,{c0,c1}] float2 for single-load corners.
__global__ void swizzle_kernel(const float* __restrict__ fg, float2* __restrict__ dst) {
    int i = blockIdx.x * blockDim.x + threadIdx.x;   // 0 .. NG*VOX
    int g = i >> 18;
    int v = i & (VOX - 1);
    float c0 = fg[(size_t)g * (2 * VOX) + v];
    float c1 = fg[(size_t)g * (2 * VOX) + VOX + v];
    dst[i] = make_float2(c0, c1);
}

template<bool USE_WS>
__global__ void amrsrn_kernel(const float* __restrict__ x,
                              const float* __restrict__ gscale,
                              const float* __restrict__ gtrans,
                              const float2* __restrict__ wsg,
                              const float* __restrict__ fg,
                              const float* __restrict__ W0,
                              const float* __restrict__ b0,
                              const float* __restrict__ W1,
                              const float* __restrict__ b1,
                              const float* __restrict__ W2,
                              const float* __restrict__ b2,
                              float* __restrict__ out) {
    int p = blockIdx.x * blockDim.x + threadIdx.x;
    float px = x[p*3+0], py = x[p*3+1], pz = x[p*3+2];

    float h0[NODES];
    #pragma unroll
    for (int j = 0; j < NODES; ++j) h0[j] = b0[j];

    // ---- positional encoding: rows 0..17 = sin(l*3+d), rows 18..35 = cos ----
    #pragma unroll
    for (int l = 0; l < 6; ++l) {
        float freq = 3.14159265358979323846f * (float)(1 << l);
        #pragma unroll
        for (int d = 0; d < 3; ++d) {
            float v = (d == 0 ? px : (d == 1 ? py : pz)) * freq;
            float s = __sinf(v), c = __cosf(v);
            const float* wrs = W0 + (l*3 + d) * NODES;
            const float* wrc = W0 + (18 + l*3 + d) * NODES;
            #pragma unroll
            for (int j = 0; j < NODES; ++j) h0[j] += s * wrs[j] + c * wrc[j];
        }
    }

    // ---- 64 grids: affine -> trilinear (align_corners=True, zeros padding) ----
    for (int g = 0; g < NG; ++g) {
        float cx = px * gscale[g*3+0] + gtrans[g*3+0];
        float cy = py * gscale[g*3+1] + gtrans[g*3+1];
        float cz = pz * gscale[g*3+2] + gtrans[g*3+2];
        float ix = (cx + 1.0f) * 31.5f;   // (c+1)*0.5*(64-1)
        float iy = (cy + 1.0f) * 31.5f;
        float iz = (cz + 1.0f) * 31.5f;
        float fxf = floorf(ix), fyf = floorf(iy), fzf = floorf(iz);
        int x0 = (int)fxf, y0 = (int)fyf, z0 = (int)fzf;
        float wx = ix - fxf, wy = iy - fyf, wz = iz - fzf;
        // some corner can be valid only if floor index in [-1, 63] on every axis
        bool any = (x0 >= -1 && x0 < GSZ) && (y0 >= -1 && y0 < GSZ) && (z0 >= -1 && z0 < GSZ);
        if (any) {
            float f0 = 0.f, f1 = 0.f;
            #pragma unroll
            for (int dz = 0; dz < 2; ++dz) {
                int zi = z0 + dz;
                bool vz = ((unsigned)zi < (unsigned)GSZ);
                int zc = min(max(zi, 0), GSZ - 1);
                float wzf = dz ? wz : 1.f - wz;
                #pragma unroll
                for (int dy = 0; dy < 2; ++dy) {
                    int yi = y0 + dy;
                    bool vy = ((unsigned)yi < (unsigned)GSZ);
                    int yc = min(max(yi, 0), GSZ - 1);
                    float wyf = dy ? wy : 1.f - wy;
                    int rowoff = (zc * GSZ + yc) * GSZ;
                    #pragma unroll
                    for (int dx = 0; dx < 2; ++dx) {
                        int xi = x0 + dx;
                        bool vx = ((unsigned)xi < (unsigned)GSZ);
                        int xc = min(max(xi, 0), GSZ - 1);
                        float w = wzf * wyf * (dx ? wx : 1.f - wx);
                        w = (vz && vy && vx) ? w : 0.f;
                        float v0, v1;
                        if (USE_WS) {
                            float2 v = wsg[(g << 18) + rowoff + xc];
                            v0 = v.x; v1 = v.y;
                        } else {
                            const float* gp = fg + ((size_t)g << 19);
                            v0 = gp[rowoff + xc];
                            v1 = gp[VOX + rowoff + xc];
                        }
                        f0 += w * v0;
                        f1 += w * v1;
                    }
                }
            }
            const float* wr = W0 + (36 + 2*g) * NODES;   // rows 36+2g, 37+2g
            #pragma unroll
            for (int j = 0; j < NODES; ++j) h0[j] += f0 * wr[j] + f1 * wr[NODES + j];
        }
    }

    // ---- snake on layer 0 output ----
    #pragma unroll
    for (int j = 0; j < NODES; ++j) {
        float s = __sinf(h0[j]);
        h0[j] = 0.5f * h0[j] + s * s;
    }

    // ---- layer 1 (two 32-wide halves to cap register pressure) + layer 2 ----
    float out_acc = b2[0];
    #pragma unroll
    for (int half = 0; half < 2; ++half) {
        float h1[32];
        #pragma unroll
        for (int j = 0; j < 32; ++j) h1[j] = b1[half*32 + j];
        #pragma unroll
        for (int i = 0; i < NODES; ++i) {
            float a = h0[i];
            const float* w1r = W1 + i * NODES + half*32;
            #pragma unroll
            for (int j = 0; j < 32; ++j) h1[j] += a * w1r[j];
        }
        #pragma unroll
        for (int j = 0; j < 32; ++j) {
            float s = __sinf(h1[j]);
            out_acc += (0.5f * h1[j] + s * s) * W2[half*32 + j];
        }
    }
    out[p] = out_acc;
}

extern "C" void kernel_launch(void* const* d_in, const int* in_sizes, int n_in,
                              void* d_out, int out_size, void* d_ws, size_t ws_size,
                              hipStream_t stream) {
    const float* x      = (const float*)d_in[0];
    const float* gscale = (const float*)d_in[1];
    const float* gtrans = (const float*)d_in[2];
    const float* fg     = (const float*)d_in[3];
    const float* W0     = (const float*)d_in[4];
    const float* b0     = (const float*)d_in[5];
    const float* W1     = (const float*)d_in[6];
    const float* b1     = (const float*)d_in[7];
    const float* W2     = (const float*)d_in[8];
    const float* b2     = (const float*)d_in[9];
    float* out = (float*)d_out;

    const size_t ws_needed = (size_t)NG * VOX * sizeof(float2);  // 128 MiB
    const bool use_ws = ws_size >= ws_needed;

    if (use_ws) {
        swizzle_kernel<<<(NG * VOX) / 256, 256, 0, stream>>>(fg, (float2*)d_ws);
        amrsrn_kernel<true><<<NPTS / 256, 256, 0, stream>>>(
            x, gscale, gtrans, (const float2*)d_ws, nullptr,
            W0, b0, W1, b1, W2, b2, out);
    } else {
        amrsrn_kernel<false><<<NPTS / 256, 256, 0, stream>>>(
            x, gscale, gtrans, nullptr, fg,
            W0, b0, W1, b1, W2, b2, out);
    }
}

// Round 2
// 534.552 us; speedup vs baseline: 1.1828x; 1.1828x over previous
//
#include <hip/hip_runtime.h>
#include <hip/hip_bf16.h>

#define NPTS    524288
#define NG      64
#define GSZ     64
#define VOX     (GSZ*GSZ*GSZ)       // 262144
#define NODES   64
#define TILE    64                  // points per block
#define NBLK    (NPTS / TILE)       // 8192
#define K0      192                 // padded K for layer-0 (164 -> 192)
#define SF      200                 // F row stride in bf16 (16B-aligned rows, 2-way-conflict only)

typedef __attribute__((ext_vector_type(8))) short bf16x8;
typedef __attribute__((ext_vector_type(4))) float f32x4;

__device__ inline unsigned short f2bf(float f) {
    __hip_bfloat16 b = __float2bfloat16(f);
    union { __hip_bfloat16 h; unsigned short u; } cv; cv.h = b;
    return cv.u;
}
__device__ inline float bflo(unsigned int v) { return __uint_as_float(v << 16); }
__device__ inline float bfhi(unsigned int v) { return __uint_as_float(v & 0xffff0000u); }

// ---- prep 1: repack [G,C,64^3] fp32 -> [G,64^3] packed bf16x2 (c0 lo, c1 hi) ----
__global__ void vox_prep(const float* __restrict__ fg, unsigned int* __restrict__ vox) {
    int i = blockIdx.x * blockDim.x + threadIdx.x;       // 0 .. NG*VOX
    int g = i >> 18;
    int v = i & (VOX - 1);
    float c0 = fg[(size_t)g * (2 * VOX) + v];
    float c1 = fg[(size_t)g * (2 * VOX) + VOX + v];
    vox[i] = (unsigned int)f2bf(c0) | ((unsigned int)f2bf(c1) << 16);
}

// ---- prep 2: W0 [164,64] -> W0t bf16 [64][192] (zero pad); W1 [64,64] -> W1t bf16 [64][64] ----
__global__ void w_prep(const float* __restrict__ W0, const float* __restrict__ W1,
                       unsigned short* __restrict__ w0t, unsigned short* __restrict__ w1t) {
    int tid = threadIdx.x;
    for (int i = tid; i < NODES * K0; i += 256) {
        int n = i / K0, k = i - n * K0;
        w0t[i] = (k < 164) ? f2bf(W0[k * NODES + n]) : (unsigned short)0;
    }
    for (int i = tid; i < NODES * NODES; i += 256) {
        int n = i >> 6, k = i & 63;
        w1t[i] = f2bf(W1[k * NODES + n]);
    }
}

// ---- main fused kernel ----
__global__ void __launch_bounds__(256, 4)
amrsrn_main(const float* __restrict__ x,
            const float* __restrict__ gscale,
            const float* __restrict__ gtrans,
            const unsigned int* __restrict__ vox,
            const unsigned short* __restrict__ w0t,
            const unsigned short* __restrict__ w1t,
            const float* __restrict__ b0,
            const float* __restrict__ b1,
            const float* __restrict__ W2,
            const float* __restrict__ b2,
            float* __restrict__ out) {
    __shared__ unsigned short Fsh[TILE * SF];   // 25600 B: feature matrix, later H
    __shared__ unsigned short wl[TILE * NG];    // 8192 B worklist (worst case)
    __shared__ float xs[TILE * 3];
    __shared__ float gss[NG * 3];
    __shared__ float gts[NG * 3];
    __shared__ int wl_cnt;

    const int tid = threadIdx.x;
    const int lane = tid & 63;
    const int gptbase = blockIdx.x * TILE;

    // ---- phase 0: zero F, stage tables ----
    for (int i = tid; i < TILE * (SF / 2); i += 256) ((unsigned int*)Fsh)[i] = 0;
    if (tid < TILE * 3) xs[tid] = x[gptbase * 3 + tid];
    if (tid < NG * 3) { gss[tid] = gscale[tid]; gts[tid] = gtrans[tid]; }
    if (tid == 0) wl_cnt = 0;
    __syncthreads();

    // ---- phase 1a: positional encoding (36 cols) ----
    {
        int pt = tid & 63;
        int grp = tid >> 6;                 // 4 groups x 9 terms = 36
        #pragma unroll
        for (int t = 0; t < 9; ++t) {
            int tau = grp * 9 + t;
            int tt = (tau < 18) ? tau : tau - 18;
            int l = tt / 3, d = tt - l * 3;
            float pv = xs[pt * 3 + d];
            float ang = pv * (3.14159265358979323846f * (float)(1 << l));
            float val = (tau < 18) ? __sinf(ang) : __cosf(ang);
            Fsh[pt * SF + tau] = f2bf(val);
        }
    }

    // ---- phase 1b: scan 64x64 pairs, push valid to worklist ----
    {
        int pt = tid & 63;
        int gbase = (tid >> 6) * 16;
        float px = xs[pt * 3 + 0], py = xs[pt * 3 + 1], pz = xs[pt * 3 + 2];
        for (int gi = 0; gi < 16; ++gi) {
            int g = gbase + gi;
            float ix = (px * gss[g * 3 + 0] + gts[g * 3 + 0] + 1.0f) * 31.5f;
            float iy = (py * gss[g * 3 + 1] + gts[g * 3 + 1] + 1.0f) * 31.5f;
            float iz = (pz * gss[g * 3 + 2] + gts[g * 3 + 2] + 1.0f) * 31.5f;
            bool valid = (ix >= -1.0f) & (ix < 64.0f)
                       & (iy >= -1.0f) & (iy < 64.0f)
                       & (iz >= -1.0f) & (iz < 64.0f);
            unsigned long long m = __ballot(valid);
            if (m) {
                int base = 0;
                if (lane == 0) base = atomicAdd(&wl_cnt, __popcll(m));
                base = __shfl(base, 0);
                if (valid) {
                    int pre = __popcll(m & ((1ull << lane) - 1ull));
                    wl[base + pre] = (unsigned short)((pt << 6) | g);
                }
            }
        }
    }
    __syncthreads();

    // ---- phase 2: process valid (pt,grid) pairs -- gather + trilerp -> F ----
    {
        int n = wl_cnt;
        for (int i = tid; i < n; i += 256) {
            int e = wl[i];
            int g = e & 63, pt = e >> 6;
            float px = xs[pt * 3 + 0], py = xs[pt * 3 + 1], pz = xs[pt * 3 + 2];
            float ix = (px * gss[g * 3 + 0] + gts[g * 3 + 0] + 1.0f) * 31.5f;
            float iy = (py * gss[g * 3 + 1] + gts[g * 3 + 1] + 1.0f) * 31.5f;
            float iz = (pz * gss[g * 3 + 2] + gts[g * 3 + 2] + 1.0f) * 31.5f;
            float fx = floorf(ix), fy = floorf(iy), fz = floorf(iz);
            int x0 = (int)fx, y0 = (int)fy, z0 = (int)fz;
            float wx = ix - fx, wy = iy - fy, wz = iz - fz;
            // per-axis (weight * validity), clamped indices (x0 in [-1,63] here)
            float wxa0 = (x0 >= 0) ? (1.0f - wx) : 0.0f;
            float wxa1 = (x0 < 63) ? wx : 0.0f;
            float wya0 = (y0 >= 0) ? (1.0f - wy) : 0.0f;
            float wya1 = (y0 < 63) ? wy : 0.0f;
            float wza0 = (z0 >= 0) ? (1.0f - wz) : 0.0f;
            float wza1 = (z0 < 63) ? wz : 0.0f;
            int xc0 = max(x0, 0), xc1 = min(x0 + 1, 63);
            int yc0 = max(y0, 0), yc1 = min(y0 + 1, 63);
            int zc0 = max(z0, 0), zc1 = min(z0 + 1, 63);
            const unsigned int* vg = vox + (g << 18);
            float f0 = 0.f, f1 = 0.f;
            #pragma unroll
            for (int dz = 0; dz < 2; ++dz) {
                int zc = dz ? zc1 : zc0; float wzv = dz ? wza1 : wza0;
                #pragma unroll
                for (int dy = 0; dy < 2; ++dy) {
                    int yc = dy ? yc1 : yc0; float wyv = dy ? wya1 : wya0;
                    int rowb = ((zc << 6) + yc) << 6;
                    float wzy = wzv * wyv;
                    #pragma unroll
                    for (int dx = 0; dx < 2; ++dx) {
                        int xc = dx ? xc1 : xc0; float wxv = dx ? wxa1 : wxa0;
                        unsigned int v = vg[rowb + xc];
                        float w = wzy * wxv;
                        f0 += w * bflo(v);
                        f1 += w * bfhi(v);
                    }
                }
            }
            unsigned int packed = (unsigned int)f2bf(f0) | ((unsigned int)f2bf(f1) << 16);
            *(unsigned int*)&Fsh[pt * SF + 36 + 2 * g] = packed;   // cols 36+2g, 37+2g
        }
    }
    __syncthreads();

    // ---- phase 3: MFMA MLP. wave w owns pts [16w, 16w+16) ----
    const int wv = tid >> 6;
    const int ptb = wv * 16;
    const int row = lane & 15;      // m (A) / n (B)
    const int quad = lane >> 4;     // k-quad
    const int koff = quad * 8;

    // layer 0: [16 x 192] @ [192 x 64]
    f32x4 acc0[4] = {{0,0,0,0},{0,0,0,0},{0,0,0,0},{0,0,0,0}};
    #pragma unroll
    for (int ks = 0; ks < 6; ++ks) {
        bf16x8 a = *(const bf16x8*)&Fsh[(ptb + row) * SF + ks * 32 + koff];
        #pragma unroll
        for (int nt = 0; nt < 4; ++nt) {
            bf16x8 b = *(const bf16x8*)&w0t[(nt * 16 + row) * K0 + ks * 32 + koff];
            acc0[nt] = __builtin_amdgcn_mfma_f32_16x16x32_bf16(a, b, acc0[nt], 0, 0, 0);
        }
    }
    // bias + snake -> H (bf16) into Fsh[pt][node]  (own rows only; wave-local)
    #pragma unroll
    for (int nt = 0; nt < 4; ++nt) {
        int node = nt * 16 + row;
        float bb = b0[node];
        #pragma unroll
        for (int r = 0; r < 4; ++r) {
            float h = acc0[nt][r] + bb;
            float s = __sinf(h);
            h = 0.5f * h + s * s;
            Fsh[(ptb + quad * 4 + r) * SF + node] = f2bf(h);
        }
    }

    // layer 1: [16 x 64] @ [64 x 64]
    f32x4 acc1[4] = {{0,0,0,0},{0,0,0,0},{0,0,0,0},{0,0,0,0}};
    #pragma unroll
    for (int ks = 0; ks < 2; ++ks) {
        bf16x8 a = *(const bf16x8*)&Fsh[(ptb + row) * SF + ks * 32 + koff];
        #pragma unroll
        for (int nt = 0; nt < 4; ++nt) {
            bf16x8 b = *(const bf16x8*)&w1t[(nt * 16 + row) * NODES + ks * 32 + koff];
            acc1[nt] = __builtin_amdgcn_mfma_f32_16x16x32_bf16(a, b, acc1[nt], 0, 0, 0);
        }
    }
    // bias + snake + dot with W2, reduce over node dim (16 lanes), write out
    float part[4] = {0.f, 0.f, 0.f, 0.f};
    #pragma unroll
    for (int nt = 0; nt < 4; ++nt) {
        int node = nt * 16 + row;
        float b1v = b1[node];
        float w2v = W2[node];
        #pragma unroll
        for (int r = 0; r < 4; ++r) {
            float h = acc1[nt][r] + b1v;
            float s = __sinf(h);
            h = 0.5f * h + s * s;
            part[r] += h * w2v;
        }
    }
    #pragma unroll
    for (int m = 1; m < 16; m <<= 1) {
        #pragma unroll
        for (int r = 0; r < 4; ++r) part[r] += __shfl_xor(part[r], m);
    }
    if (row == 0) {
        float b2v = b2[0];
        int gp = gptbase + ptb + quad * 4;
        #pragma unroll
        for (int r = 0; r < 4; ++r) out[gp + r] = part[r] + b2v;
    }
}

// ---- fallback (no workspace): round-1 style direct fp32 kernel ----
__global__ void amrsrn_fallback(const float* __restrict__ x,
                                const float* __restrict__ gscale,
                                const float* __restrict__ gtrans,
                                const float* __restrict__ fg,
                                const float* __restrict__ W0,
                                const float* __restrict__ b0,
                                const float* __restrict__ W1,
                                const float* __restrict__ b1,
                                const float* __restrict__ W2,
                                const float* __restrict__ b2,
                                float* __restrict__ out) {
    int p = blockIdx.x * blockDim.x + threadIdx.x;
    float px = x[p*3+0], py = x[p*3+1], pz = x[p*3+2];
    float h0[NODES];
    #pragma unroll
    for (int j = 0; j < NODES; ++j) h0[j] = b0[j];
    #pragma unroll
    for (int l = 0; l < 6; ++l) {
        float freq = 3.14159265358979323846f * (float)(1 << l);
        #pragma unroll
        for (int d = 0; d < 3; ++d) {
            float v = (d == 0 ? px : (d == 1 ? py : pz)) * freq;
            float s = __sinf(v), c = __cosf(v);
            const float* wrs = W0 + (l*3 + d) * NODES;
            const float* wrc = W0 + (18 + l*3 + d) * NODES;
            #pragma unroll
            for (int j = 0; j < NODES; ++j) h0[j] += s * wrs[j] + c * wrc[j];
        }
    }
    for (int g = 0; g < NG; ++g) {
        float cx = px * gscale[g*3+0] + gtrans[g*3+0];
        float cy = py * gscale[g*3+1] + gtrans[g*3+1];
        float cz = pz * gscale[g*3+2] + gtrans[g*3+2];
        float ix = (cx + 1.0f) * 31.5f, iy = (cy + 1.0f) * 31.5f, iz = (cz + 1.0f) * 31.5f;
        float fxf = floorf(ix), fyf = floorf(iy), fzf = floorf(iz);
        int x0 = (int)fxf, y0 = (int)fyf, z0 = (int)fzf;
        float wx = ix - fxf, wy = iy - fyf, wz = iz - fzf;
        bool any = (x0 >= -1 && x0 < GSZ) && (y0 >= -1 && y0 < GSZ) && (z0 >= -1 && z0 < GSZ);
        if (any) {
            float f0 = 0.f, f1 = 0.f;
            #pragma unroll
            for (int dz = 0; dz < 2; ++dz) {
                int zi = z0 + dz; bool vz = ((unsigned)zi < (unsigned)GSZ);
                int zc = min(max(zi, 0), GSZ - 1);
                float wzf = dz ? wz : 1.f - wz;
                #pragma unroll
                for (int dy = 0; dy < 2; ++dy) {
                    int yi = y0 + dy; bool vy = ((unsigned)yi < (unsigned)GSZ);
                    int yc = min(max(yi, 0), GSZ - 1);
                    float wyf = dy ? wy : 1.f - wy;
                    int rowoff = (zc * GSZ + yc) * GSZ;
                    #pragma unroll
                    for (int dx = 0; dx < 2; ++dx) {
                        int xi = x0 + dx; bool vx = ((unsigned)xi < (unsigned)GSZ);
                        int xc = min(max(xi, 0), GSZ - 1);
                        float w = wzf * wyf * (dx ? wx : 1.f - wx);
                        w = (vz && vy && vx) ? w : 0.f;
                        const float* gp = fg + ((size_t)g << 19);
                        f0 += w * gp[rowoff + xc];
                        f1 += w * gp[VOX + rowoff + xc];
                    }
                }
            }
            const float* wr = W0 + (36 + 2*g) * NODES;
            #pragma unroll
            for (int j = 0; j < NODES; ++j) h0[j] += f0 * wr[j] + f1 * wr[NODES + j];
        }
    }
    #pragma unroll
    for (int j = 0; j < NODES; ++j) { float s = __sinf(h0[j]); h0[j] = 0.5f * h0[j] + s * s; }
    float out_acc = b2[0];
    #pragma unroll
    for (int half = 0; half < 2; ++half) {
        float h1[32];
        #pragma unroll
        for (int j = 0; j < 32; ++j) h1[j] = b1[half*32 + j];
        #pragma unroll
        for (int i = 0; i < NODES; ++i) {
            float a = h0[i];
            const float* w1r = W1 + i * NODES + half*32;
            #pragma unroll
            for (int j = 0; j < 32; ++j) h1[j] += a * w1r[j];
        }
        #pragma unroll
        for (int j = 0; j < 32; ++j) { float s = __sinf(h1[j]); out_acc += (0.5f * h1[j] + s * s) * W2[half*32 + j]; }
    }
    out[p] = out_acc;
}

extern "C" void kernel_launch(void* const* d_in, const int* in_sizes, int n_in,
                              void* d_out, int out_size, void* d_ws, size_t ws_size,
                              hipStream_t stream) {
    const float* x      = (const float*)d_in[0];
    const float* gscale = (const float*)d_in[1];
    const float* gtrans = (const float*)d_in[2];
    const float* fg     = (const float*)d_in[3];
    const float* W0     = (const float*)d_in[4];
    const float* b0     = (const float*)d_in[5];
    const float* W1     = (const float*)d_in[6];
    const float* b1     = (const float*)d_in[7];
    const float* W2     = (const float*)d_in[8];
    const float* b2     = (const float*)d_in[9];
    float* out = (float*)d_out;

    const size_t vox_bytes = (size_t)NG * VOX * sizeof(unsigned int);       // 64 MiB
    const size_t w0t_bytes = (size_t)NODES * K0 * sizeof(unsigned short);   // 24 KiB
    const size_t w1t_bytes = (size_t)NODES * NODES * sizeof(unsigned short);// 8 KiB
    const size_t ws_needed = vox_bytes + w0t_bytes + w1t_bytes;

    if (ws_size >= ws_needed) {
        unsigned int*   vox = (unsigned int*)d_ws;
        unsigned short* w0t = (unsigned short*)((char*)d_ws + vox_bytes);
        unsigned short* w1t = w0t + NODES * K0;
        vox_prep<<<(NG * VOX) / 256, 256, 0, stream>>>(fg, vox);
        w_prep<<<1, 256, 0, stream>>>(W0, W1, w0t, w1t);
        amrsrn_main<<<NBLK, 256, 0, stream>>>(x, gscale, gtrans, vox, w0t, w1t,
                                              b0, b1, W2, b2, out);
    } else {
        amrsrn_fallback<<<NPTS / 256, 256, 0, stream>>>(
            x, gscale, gtrans, fg, W0, b0, W1, b1, W2, b2, out);
    }
}